// Round 14
// baseline (236.732 us; speedup 1.0000x reference)
//
#include <hip/hip_runtime.h>
#include <math.h>

#define B_ 4
#define L_ 2048
#define DM 1024
#define H_ 16
#define HD_ 64
#define NH_ 64            // B_*H_
#define EPS_ 1e-6f

typedef float f32x4 __attribute__((ext_vector_type(4)));
typedef _Float16 half8 __attribute__((ext_vector_type(8)));
typedef _Float16 half4 __attribute__((ext_vector_type(4)));

typedef __attribute__((address_space(3))) void lds_v;
typedef const __attribute__((address_space(1))) void glb_v;
#define GLOAD16(g, l) __builtin_amdgcn_global_load_lds((glb_v*)(g), (lds_v*)(l), 16, 0, 0)

__device__ __forceinline__ float sigmoidf_(float x) { return 1.0f / (1.0f + expf(-x)); }

// ---------------------------------------------------------------------------
// prep: x -> f16 | weights -> f16 | zero kvb + sums.  One launch.
// ---------------------------------------------------------------------------
__global__ __launch_bounds__(256) void prep_kernel(
    const float* __restrict__ x,
    const float* __restrict__ Wq, const float* __restrict__ Wk,
    const float* __restrict__ Wv, const float* __restrict__ Wo,
    _Float16* __restrict__ xf, _Float16* __restrict__ wh3, _Float16* __restrict__ woh,
    float* __restrict__ sums, float* __restrict__ kvb)
{
    const int bid = (int)blockIdx.x;
    const int tid = threadIdx.x;
    if (bid < 8192) {
        const int i = bid * 256 + tid;
        f32x4 v = *(const f32x4*)(x + (size_t)i * 4);
        half4 h = { (_Float16)v[0], (_Float16)v[1], (_Float16)v[2], (_Float16)v[3] };
        *(half4*)(xf + (size_t)i * 4) = h;
        if (bid < 1024) kvb[bid * 256 + tid] = 0.f;
        if (bid < 64)   sums[bid * 256 + tid] = 0.f;
    } else {
        const int r = bid - 8192;
        const int y = r >> 10;
        const int i = (r & 1023) * 256 + tid;
        const float* src = (y == 0) ? Wq : (y == 1) ? Wk : (y == 2) ? Wv : Wo;
        _Float16* hh = (y < 3) ? (wh3 + (size_t)y * DM * DM) : woh;
        f32x4 v = *(const f32x4*)(src + (size_t)i * 4);
        half4 h = { (_Float16)v[0], (_Float16)v[1], (_Float16)v[2], (_Float16)v[3] };
        *(half4*)(hh + (size_t)i * 4) = h;
    }
}

// ===========================================================================
// QKV GEMM v2: single-product f16, BM=BN=256, BK=64, 8 waves (2M x 4N),
//   wave tile 128x64 (acc[8][4]) — per kstep 12 ds_read feed 32 MFMA
//   (LDS/MFMA balanced).  2-phase double-buffer: STAGE(t+1) before
//   compute(t), ONE __syncthreads() per K-tile.  LDS 2 x 64 KB = 128 KB.
//   Swizzle: 16B slot' = slot ^ (row&7) within 128B rows (conflict-free
//   minimum); linear gload dest + inverse-swizzled global source.
//   Grid 384 = 8 XCDs x 48.  Epilogue: +bias, sigmoid q/k, [B,H,L,HD] f16
//   scatter, fused post-sigmoid colsum (256 cols) -> atomicAdd.
// ===========================================================================
__global__ __launch_bounds__(512, 2) void gemm_qkv_kernel(
    const _Float16* __restrict__ xf,
    const _Float16* __restrict__ wh,                               // [3][DM][DM]
    const float* __restrict__ bq, const float* __restrict__ bk, const float* __restrict__ bv,
    _Float16* __restrict__ qb, _Float16* __restrict__ kb, _Float16* __restrict__ vb,
    float* __restrict__ qsum, float* __restrict__ ksum)
{
    const int bid = (int)blockIdx.x;
    const int wg = (bid & 7) * 48 + (bid >> 3);    // bijective, 384 % 8 == 0
    const int by = wg & 31;                        // 32 row-blocks of 256
    const int bx = wg >> 5;                        // 12 col-blocks of 256
    const int row0 = by * 256;
    const int z = bx >> 2;                         // 0:q 1:k 2:v
    const int colz = (bx & 3) * 256;               // col offset within z
    const float* __restrict__ bias  = (z == 0) ? bq : (z == 1) ? bk : bv;
    _Float16* __restrict__ outp     = (z == 0) ? qb : (z == 1) ? kb : vb;
    const _Float16* Wh = wh + (size_t)z * DM * DM;

    __shared__ _Float16 lds[2 * 32768];   // dbuf x (A 32KB | B 32KB)
    const int t = threadIdx.x;
    const int lane = t & 63;
    const int w = t >> 6;                 // 0..7
    const int wr = w >> 2;                // 0..1  (M)
    const int wc = w & 3;                 // 0..3  (N)
    const int fr = lane & 15, kc = lane >> 4;

    auto STAGE = [&](int k0, int buf) {
        const _Float16* a_g = xf + (size_t)row0 * DM + k0;
        const _Float16* b_g = Wh + (size_t)colz * DM + k0;
        _Float16* dst = lds + buf * 32768;
        #pragma unroll
        for (int p = 0; p < 4; ++p) {
            const int b = p * 8192 + t * 16;          // byte in 32 KB plane
            const int r = b >> 7;                     // row 0..255
            const int s = (b >> 4) & 7;               // 16B slot in 128B row
            const int c = ((s ^ (r & 7)) << 3);       // inverse-swizzled k-elem
            const size_t go = (size_t)r * DM + c;
            GLOAD16(a_g + go, dst + (b >> 1));
            GLOAD16(b_g + go, dst + 16384 + (b >> 1));
        }
    };

    f32x4 acc[8][4];
    #pragma unroll
    for (int m = 0; m < 8; ++m)
        #pragma unroll
        for (int n = 0; n < 4; ++n) acc[m][n] = f32x4{0.f, 0.f, 0.f, 0.f};

    STAGE(0, 0);
    __syncthreads();

    for (int kt = 0; kt < 16; ++kt) {
        if (kt + 1 < 16) STAGE((kt + 1) * 64, (kt + 1) & 1);
        const _Float16* bufA = lds + (kt & 1) * 32768;
        const _Float16* bufB = bufA + 16384;
        #pragma unroll
        for (int ks = 0; ks < 2; ++ks) {
            const int sl = (ks << 2) | kc;
            half8 bf[4];
            #pragma unroll
            for (int n = 0; n < 4; ++n) {
                const int row = wc * 64 + n * 16 + fr;
                bf[n] = *(const half8*)(bufB + row * 64 + ((sl ^ (row & 7)) << 3));
            }
            #pragma unroll
            for (int m = 0; m < 8; ++m) {
                const int row = wr * 128 + m * 16 + fr;
                half8 af = *(const half8*)(bufA + row * 64 + ((sl ^ (row & 7)) << 3));
                #pragma unroll
                for (int n = 0; n < 4; ++n)
                    acc[m][n] = __builtin_amdgcn_mfma_f32_16x16x32_f16(af, bf[n], acc[m][n], 0, 0, 0);
            }
        }
        __syncthreads();   // drains prefetch + releases buffers
    }

    float csum[4] = {0.f, 0.f, 0.f, 0.f};
    #pragma unroll
    for (int m = 0; m < 8; ++m) {
        const int gr0 = row0 + wr * 128 + m * 16 + kc * 4;
        #pragma unroll
        for (int n = 0; n < 4; ++n) {
            const int j = colz + wc * 64 + n * 16 + fr;
            const float bj = bias[j];
            const int h = j >> 6, dd = j & 63;
            #pragma unroll
            for (int r2 = 0; r2 < 4; ++r2) {
                const int i = gr0 + r2;
                const int nn = i >> 11, l = i & (L_ - 1);
                float v = acc[m][n][r2] + bj;
                if (z < 2) { v = sigmoidf_(v); csum[n] += v; }
                outp[(((size_t)(nn * H_ + h)) * L_ + l) * HD_ + dd] = (_Float16)v;
            }
        }
    }

    if (z < 2) {
        float* scol = (float*)lds;             // LDS free after final barrier
        if (t < 256) scol[t] = 0.f;
        __syncthreads();
        #pragma unroll
        for (int n = 0; n < 4; ++n)
            atomicAdd(&scol[wc * 64 + n * 16 + fr], csum[n]);
        __syncthreads();
        if (t < 256) {
            const int j = colz + t;
            const int nn = row0 >> 11;
            float* dst = (z == 0) ? qsum : ksum;
            atomicAdd(&dst[(nn * H_ + (j >> 6)) * 64 + (j & 63)], scol[t]);
        }
    }
}

// ===========================================================================
// Output GEMM: single-product f16, BK=64, 2-phase dbuf, XCD grid (512 = 8x64)
// (proven R13 — unchanged)
// ===========================================================================
__global__ __launch_bounds__(256) void gemm_out_kernel(
    const _Float16* __restrict__ af, const _Float16* __restrict__ wo,
    const float* __restrict__ bias, float* __restrict__ outp)
{
    const int bid = (int)blockIdx.x;
    const int wg = (bid & 7) * 64 + (bid >> 3);
    const int row0 = (wg >> 3) * 128;
    const int col0 = (wg & 7) * 128;

    __shared__ _Float16 lds[2 * 16384];
    const int t = threadIdx.x;
    const int lane = t & 63;
    const int w = t >> 6;
    const int wr = w >> 1, wc = w & 1;
    const int fr = lane & 15, kc = lane >> 4;

    auto STAGE = [&](int k0, int buf) {
        const _Float16* a_g = af + (size_t)row0 * DM + k0;
        const _Float16* b_g = wo + (size_t)col0 * DM + k0;
        _Float16* dst = lds + buf * 16384;
        #pragma unroll
        for (int p = 0; p < 4; ++p) {
            const int b = p * 4096 + t * 16;
            const int r = b >> 7;
            const int s = (b >> 4) & 7;
            const int c = ((s ^ (r & 7)) << 3);
            const size_t go = (size_t)r * DM + c;
            GLOAD16(a_g + go, dst + (b >> 1));
            GLOAD16(b_g + go, dst + 8192 + (b >> 1));
        }
    };

    f32x4 acc[4][4];
    #pragma unroll
    for (int m = 0; m < 4; ++m)
        #pragma unroll
        for (int n = 0; n < 4; ++n) acc[m][n] = f32x4{0.f, 0.f, 0.f, 0.f};

    STAGE(0, 0);
    __syncthreads();

    for (int kt = 0; kt < 16; ++kt) {
        if (kt + 1 < 16) STAGE((kt + 1) * 64, (kt + 1) & 1);
        const _Float16* bufA = lds + (kt & 1) * 16384;
        const _Float16* bufB = bufA + 8192;
        #pragma unroll
        for (int ks = 0; ks < 2; ++ks) {
            const int sl = (ks << 2) | kc;
            half8 bf[4];
            #pragma unroll
            for (int n = 0; n < 4; ++n) {
                const int row = wc * 64 + n * 16 + fr;
                bf[n] = *(const half8*)(bufB + row * 64 + ((sl ^ (row & 7)) << 3));
            }
            #pragma unroll
            for (int m = 0; m < 4; ++m) {
                const int row = wr * 64 + m * 16 + fr;
                half8 af8 = *(const half8*)(bufA + row * 64 + ((sl ^ (row & 7)) << 3));
                #pragma unroll
                for (int n = 0; n < 4; ++n)
                    acc[m][n] = __builtin_amdgcn_mfma_f32_16x16x32_f16(af8, bf[n], acc[m][n], 0, 0, 0);
            }
        }
        __syncthreads();
    }

    #pragma unroll
    for (int m = 0; m < 4; ++m) {
        const int gr0 = row0 + wr * 64 + m * 16 + kc * 4;
        #pragma unroll
        for (int n = 0; n < 4; ++n) {
            const int j = col0 + wc * 64 + n * 16 + fr;
            const float bj = bias[j];
            #pragma unroll
            for (int r2 = 0; r2 < 4; ++r2)
                outp[(size_t)(gr0 + r2) * DM + j] = acc[m][n][r2] + bj;
        }
    }
}

// ---------------------------------------------------------------------------
// stage1 — rowgroup-8 dots (proven R12)
// ---------------------------------------------------------------------------
__global__ __launch_bounds__(256) void stage1_kernel(
    const _Float16* __restrict__ q, const _Float16* __restrict__ k,
    const float* __restrict__ qsum, const float* __restrict__ ksum,
    float* __restrict__ si, float* __restrict__ qsi, float* __restrict__ kso)
{
    const int nh = blockIdx.x, ch = blockIdx.y;
    const _Float16* qp = q + (size_t)nh * L_ * HD_;
    const _Float16* kp = k + (size_t)nh * L_ * HD_;
    const int tid = threadIdx.x;
    const int lane = tid & 63;
    const int w = tid >> 6;
    const int r8 = lane >> 3;
    const int oct = lane & 7;

    __shared__ float ksum_s[64], qsum_s[64];
    __shared__ float s1[4][64], s2[4][64];
    if (tid < 64) {
        ksum_s[tid] = ksum[nh * 64 + tid] + EPS_;
        qsum_s[tid] = qsum[nh * 64 + tid] + EPS_;
    }
    __syncthreads();

    float qacc[8] = {0.f}, kacc[8] = {0.f};
    #pragma unroll
    for (int it = 0; it < 8; ++it) {
        const int l = ch * 256 + it * 32 + w * 8 + r8;
        half8 q8 = *(const half8*)(qp + (size_t)l * HD_ + oct * 8);
        half8 k8 = *(const half8*)(kp + (size_t)l * HD_ + oct * 8);
        float a = 0.f, b = 0.f;
        #pragma unroll
        for (int j = 0; j < 8; ++j) {
            a += ((float)q8[j] + EPS_) * ksum_s[oct * 8 + j];
            b += ((float)k8[j] + EPS_) * qsum_s[oct * 8 + j];
        }
        a += __shfl_xor(a, 1); a += __shfl_xor(a, 2); a += __shfl_xor(a, 4);
        b += __shfl_xor(b, 1); b += __shfl_xor(b, 2); b += __shfl_xor(b, 4);
        const float siv = 1.f / a;
        const float sov = 1.f / b;
        if (oct == 0) si[nh * L_ + l] = siv;
        #pragma unroll
        for (int j = 0; j < 8; ++j) {
            qacc[j] += (float)q8[j] * siv;
            kacc[j] += (float)k8[j] * sov;
        }
    }
    #pragma unroll
    for (int j = 0; j < 8; ++j) {
        qacc[j] += __shfl_xor(qacc[j], 8);  qacc[j] += __shfl_xor(qacc[j], 16); qacc[j] += __shfl_xor(qacc[j], 32);
        kacc[j] += __shfl_xor(kacc[j], 8);  kacc[j] += __shfl_xor(kacc[j], 16); kacc[j] += __shfl_xor(kacc[j], 32);
    }
    if (r8 == 0) {
        #pragma unroll
        for (int j = 0; j < 8; ++j) { s1[w][oct * 8 + j] = qacc[j]; s2[w][oct * 8 + j] = kacc[j]; }
    }
    __syncthreads();
    if (tid < 64) {
        atomicAdd(&qsi[nh * 64 + tid], s1[0][tid] + s1[1][tid] + s1[2][tid] + s1[3][tid]);
        atomicAdd(&kso[nh * 64 + tid], s2[0][tid] + s2[1][tid] + s2[2][tid] + s2[3][tid]);
    }
}

// ---------------------------------------------------------------------------
// kv partial with fused source-competition; atomicAdd into kvb (proven R13)
// ---------------------------------------------------------------------------
__global__ __launch_bounds__(256) void kv_part_kernel(
    const _Float16* __restrict__ k, const _Float16* __restrict__ v,
    const float* __restrict__ qsi, float* __restrict__ kvb, float* __restrict__ psum_p)
{
    const int nh = blockIdx.x, ch = blockIdx.y;
    const _Float16* kp = k + (size_t)nh * L_ * HD_;
    const _Float16* vp = v + (size_t)nh * L_ * HD_;
    const int tid = threadIdx.x;
    const int lane = tid & 63;
    const int w = tid >> 6;
    const int row8 = tid >> 3;
    const int oct = tid & 7;

    __shared__ float qsi_s[64];
    __shared__ float ks[32][65], vs[32][65];
    __shared__ float pl[32];
    if (tid < 64) qsi_s[tid] = qsi[nh * 64 + tid] + EPS_;
    __syncthreads();

    float acc[16] = {0.f};
    float psum_acc = 0.f;
    for (int l0 = ch * 256; l0 < (ch + 1) * 256; l0 += 32) {
        {
            const half8* kp8 = (const half8*)(kp + (size_t)l0 * HD_);
            const half8* vp8 = (const half8*)(vp + (size_t)l0 * HD_);
            half8 k8 = kp8[tid];
            half8 v8 = vp8[tid];
            const int r = tid >> 3, c = (tid & 7) * 8;
            #pragma unroll
            for (int j = 0; j < 8; ++j) {
                ks[r][c + j] = (float)k8[j];
                vs[r][c + j] = (float)v8[j];
            }
        }
        __syncthreads();
        {
            float b = 0.f;
            #pragma unroll
            for (int j = 0; j < 8; ++j)
                b += (ks[row8][oct * 8 + j] + EPS_) * qsi_s[oct * 8 + j];
            b += __shfl_xor(b, 1); b += __shfl_xor(b, 2); b += __shfl_xor(b, 4);
            b = fminf(1.f, fmaxf(-1.f, b));
            const float p = expf(b);
            if (oct == 0) { pl[row8] = p; psum_acc += p; }
        }
        __syncthreads();
        #pragma unroll 4
        for (int ll = 0; ll < 32; ++ll) {
            const float vv = vs[ll][lane] * pl[ll];
            #pragma unroll
            for (int dd = 0; dd < 16; ++dd) acc[dd] += ks[ll][w * 16 + dd] * vv;
        }
        __syncthreads();
    }
    #pragma unroll
    for (int dd = 0; dd < 16; ++dd)
        atomicAdd(&kvb[(size_t)nh * 4096 + (w * 16 + dd) * 64 + lane], acc[dd]);

    psum_acc += __shfl_xor(psum_acc, 8);
    psum_acc += __shfl_xor(psum_acc, 16);
    psum_acc += __shfl_xor(psum_acc, 32);
    psum_acc += __shfl_xor(psum_acc, 1);
    psum_acc += __shfl_xor(psum_acc, 2);
    psum_acc += __shfl_xor(psum_acc, 4);
    __shared__ float sp[4];
    if (lane == 0) sp[w] = psum_acc;
    __syncthreads();
    if (tid == 0) psum_p[nh * 8 + ch] = sp[0] + sp[1] + sp[2] + sp[3];
}

// ---------------------------------------------------------------------------
// out with fused sink_allocation + deferred softmax scale; f16 attn store
// ---------------------------------------------------------------------------
__global__ __launch_bounds__(256) void out_kernel(
    const _Float16* __restrict__ q, const float* __restrict__ kvb,
    const float* __restrict__ si, const float* __restrict__ kso,
    const float* __restrict__ psum_p,
    _Float16* __restrict__ attn_f)
{
    const int nh = blockIdx.x;
    const int n = nh >> 4;
    const int h = nh & 15;
    const int l0 = blockIdx.y * 64;
    __shared__ float kvs[64][64];
    __shared__ float qs[64][65];
    __shared__ float sal[64];
    __shared__ float kso_s[64];
    const int tid = threadIdx.x;
    float tot = 0.f;
    #pragma unroll
    for (int c = 0; c < 8; ++c) tot += psum_p[nh * 8 + c];
    const float scale = (float)L_ / tot;
    for (int i = tid; i < 4096; i += 256)
        kvs[i >> 6][i & 63] = kvb[(size_t)nh * 4096 + i];
    {
        const half8* src8 = (const half8*)(q + ((size_t)nh * L_ + l0) * HD_);
        for (int i = tid; i < 512; i += 256) {
            half8 v8 = src8[i];
            const int r = i >> 3, c = (i & 7) * 8;
            #pragma unroll
            for (int j = 0; j < 8; ++j) qs[r][c + j] = (float)v8[j];
        }
    }
    if (tid < 64) kso_s[tid] = kso[nh * 64 + tid] + EPS_;
    __syncthreads();
    {
        const int row = tid >> 3;           // 0..31
        const int oct = tid & 7;
        #pragma unroll
        for (int rr = 0; rr < 2; ++rr) {
            const int r = rr * 32 + row;
            float a = 0.f;
            #pragma unroll
            for (int j = 0; j < 8; ++j)
                a += (qs[r][oct * 8 + j] + EPS_) * kso_s[oct * 8 + j];
            a += __shfl_xor(a, 1); a += __shfl_xor(a, 2); a += __shfl_xor(a, 4);
            if (oct == 0) sal[r] = sigmoidf_(a);
        }
    }
    __syncthreads();
    const int lane = tid & 63;
    const int w = tid >> 6;
    for (int ll = w; ll < 64; ll += 4) {
        const int l = l0 + ll;
        float acc = 0.f;
        #pragma unroll
        for (int d = 0; d < 64; ++d) acc += qs[ll][d] * kvs[d][lane];
        const float val = acc * si[nh * L_ + l] * sal[ll] * scale;
        attn_f[((size_t)n * L_ + l) * DM + h * 64 + lane] = (_Float16)val;
    }
}

extern "C" void kernel_launch(void* const* d_in, const int* in_sizes, int n_in,
                              void* d_out, int out_size, void* d_ws, size_t ws_size,
                              hipStream_t stream)
{
    const float* x  = (const float*)d_in[0];
    const float* Wq = (const float*)d_in[1];
    const float* bq = (const float*)d_in[2];
    const float* Wk = (const float*)d_in[3];
    const float* bk = (const float*)d_in[4];
    const float* Wv = (const float*)d_in[5];
    const float* bv = (const float*)d_in[6];
    const float* Wo = (const float*)d_in[7];
    const float* bo = (const float*)d_in[8];
    float* out = (float*)d_out;

    float* ws = (float*)d_ws;
    size_t off = 0;
    const size_t big = (size_t)B_ * L_ * DM;   // 8,388,608 elems
    _Float16* qbuf = (_Float16*)(ws + off); off += big / 2;
    _Float16* kbuf = (_Float16*)(ws + off); off += big / 2;
    _Float16* vbuf = (_Float16*)(ws + off); off += big / 2;
    _Float16* xf = (_Float16*)(ws + off);
    _Float16* attn_f = xf;
    off += big / 2;
    _Float16* wh3 = (_Float16*)(ws + off); off += (size_t)3 * DM * DM / 2;
    _Float16* woh = (_Float16*)(ws + off); off += (size_t)DM * DM / 2;
    float* kvb    = ws + off; off += (size_t)NH_ * 64 * 64;
    float* sums = ws + off;
    float* qsum = sums;
    float* ksum = sums + 1 * NH_ * 64;
    float* qsi  = sums + 2 * NH_ * 64;
    float* kso  = sums + 3 * NH_ * 64;
    off += 4 * NH_ * 64;
    float* psum_p = ws + off; off += NH_ * 8;
    float* si     = ws + off; off += NH_ * L_;

    // 1. prep: x -> f16, weights -> f16, zero kvb + accumulators
    prep_kernel<<<12288, 256, 0, stream>>>(x, Wq, Wk, Wv, Wo, xf, wh3, woh, sums, kvb);

    // 2. QKV projection GEMM v2 (256x256 tile, 8x4 wave blocking, 2-phase)
    gemm_qkv_kernel<<<384, 512, 0, stream>>>(xf, wh3, bq, bk, bv,
                                             qbuf, kbuf, vbuf, qsum, ksum);

    // 3. stage1 (rowgroup dots; si + qsi/kso atomics)
    stage1_kernel<<<dim3(NH_, 8), 256, 0, stream>>>(qbuf, kbuf, qsum, ksum, si, qsi, kso);

    // 4. kv with fused source-competition -> atomicAdd into kvb
    kv_part_kernel<<<dim3(NH_, 8), 256, 0, stream>>>(kbuf, vbuf, qsi, kvb, psum_p);

    // 5. out with fused sink_allocation + softmax scale -> f16 attn
    out_kernel<<<dim3(NH_, L_ / 64), 256, 0, stream>>>(qbuf, kvb, si, kso, psum_p, attn_f);

    // 6. output projection GEMM (2-phase dbuf, single-product f16)
    gemm_out_kernel<<<512, 256, 0, stream>>>(attn_f, woh, bo, out);
}

// Round 15
// 218.228 us; speedup vs baseline: 1.0848x; 1.0848x over previous
//
#include <hip/hip_runtime.h>
#include <math.h>

#define B_ 4
#define L_ 2048
#define DM 1024
#define H_ 16
#define HD_ 64
#define NH_ 64            // B_*H_
#define EPS_ 1e-6f

typedef float f32x4 __attribute__((ext_vector_type(4)));
typedef _Float16 half8 __attribute__((ext_vector_type(8)));
typedef _Float16 half4 __attribute__((ext_vector_type(4)));

typedef __attribute__((address_space(3))) void lds_v;
typedef const __attribute__((address_space(1))) void glb_v;
#define GLOAD16(g, l) __builtin_amdgcn_global_load_lds((glb_v*)(g), (lds_v*)(l), 16, 0, 0)

// fast native transcendentals: v_exp_f32 path + v_rcp_f32.
// |err| ~1ulp relative — far below the 4.88e-4 pipeline floor.
__device__ __forceinline__ float fexp_(float x)     { return __expf(x); }
__device__ __forceinline__ float sigmoidf_(float x) { return __builtin_amdgcn_rcpf(1.0f + __expf(-x)); }

// ---------------------------------------------------------------------------
// prep: x -> f16 | weights -> f16 | zero kvb + sums.  One launch.
// ---------------------------------------------------------------------------
__global__ __launch_bounds__(256) void prep_kernel(
    const float* __restrict__ x,
    const float* __restrict__ Wq, const float* __restrict__ Wk,
    const float* __restrict__ Wv, const float* __restrict__ Wo,
    _Float16* __restrict__ xf, _Float16* __restrict__ wh3, _Float16* __restrict__ woh,
    float* __restrict__ sums, float* __restrict__ kvb)
{
    const int bid = (int)blockIdx.x;
    const int tid = threadIdx.x;
    if (bid < 8192) {
        const int i = bid * 256 + tid;
        f32x4 v = *(const f32x4*)(x + (size_t)i * 4);
        half4 h = { (_Float16)v[0], (_Float16)v[1], (_Float16)v[2], (_Float16)v[3] };
        *(half4*)(xf + (size_t)i * 4) = h;
        if (bid < 1024) kvb[bid * 256 + tid] = 0.f;
        if (bid < 64)   sums[bid * 256 + tid] = 0.f;
    } else {
        const int r = bid - 8192;
        const int y = r >> 10;
        const int i = (r & 1023) * 256 + tid;
        const float* src = (y == 0) ? Wq : (y == 1) ? Wk : (y == 2) ? Wv : Wo;
        _Float16* hh = (y < 3) ? (wh3 + (size_t)y * DM * DM) : woh;
        f32x4 v = *(const f32x4*)(src + (size_t)i * 4);
        half4 h = { (_Float16)v[0], (_Float16)v[1], (_Float16)v[2], (_Float16)v[3] };
        *(half4*)(hh + (size_t)i * 4) = h;
    }
}

// ===========================================================================
// QKV GEMM (proven R13): single-product f16, 128x128 tile, BK=64, 2-phase
//   double-buffer (STAGE(t+1) before compute(t), ONE barrier per K-tile).
//   LDS 2 x 32 KB = 64 KB.  Swizzle slot' = slot^(row&7) on 16B slots of
//   128B rows; linear gload dest + inverse-swizzled global source.
//   XCD-swizzled 1D grid (1536 = 8 x 192).  Epilogue: +bias, fast sigmoid
//   q/k, [B,H,L,HD] f16 scatter, fused post-sigmoid colsum -> atomicAdd.
// ===========================================================================
__global__ __launch_bounds__(256) void gemm_qkv_kernel(
    const _Float16* __restrict__ xf,
    const _Float16* __restrict__ wh,                               // [3][DM][DM]
    const float* __restrict__ bq, const float* __restrict__ bk, const float* __restrict__ bv,
    _Float16* __restrict__ qb, _Float16* __restrict__ kb, _Float16* __restrict__ vb,
    float* __restrict__ qsum, float* __restrict__ ksum)
{
    const int bid = (int)blockIdx.x;
    const int wg = (bid & 7) * 192 + (bid >> 3);   // bijective, 1536 % 8 == 0
    const int z = wg / 512;
    const int rem = wg & 511;
    const int row0 = (rem >> 3) * 128;
    const int col0 = (rem & 7) * 128;
    const float* __restrict__ bias  = (z == 0) ? bq : (z == 1) ? bk : bv;
    _Float16* __restrict__ outp     = (z == 0) ? qb : (z == 1) ? kb : vb;
    const _Float16* Wh = wh + (size_t)z * DM * DM;

    __shared__ _Float16 lds[2 * 16384];   // dbuf x (A 16KB | B 16KB)
    const int t = threadIdx.x;
    const int lane = t & 63;
    const int w = t >> 6;
    const int wr = w >> 1, wc = w & 1;
    const int fr = lane & 15, kc = lane >> 4;

    auto STAGE = [&](int k0, int buf) {
        const _Float16* a_g = xf + (size_t)row0 * DM + k0;
        const _Float16* b_g = Wh + (size_t)col0 * DM + k0;
        _Float16* dst = lds + buf * 16384;
        #pragma unroll
        for (int p = 0; p < 4; ++p) {
            const int b = p * 4096 + t * 16;          // byte in 16 KB plane
            const int r = b >> 7;                     // row 0..127
            const int s = (b >> 4) & 7;               // 16B slot in 128B row
            const int c = ((s ^ (r & 7)) << 3);       // inverse-swizzled k-elem
            const size_t go = (size_t)r * DM + c;
            GLOAD16(a_g + go, dst + (b >> 1));
            GLOAD16(b_g + go, dst + 8192 + (b >> 1));
        }
    };

    f32x4 acc[4][4];
    #pragma unroll
    for (int m = 0; m < 4; ++m)
        #pragma unroll
        for (int n = 0; n < 4; ++n) acc[m][n] = f32x4{0.f, 0.f, 0.f, 0.f};

    STAGE(0, 0);
    __syncthreads();

    for (int kt = 0; kt < 16; ++kt) {
        if (kt + 1 < 16) STAGE((kt + 1) * 64, (kt + 1) & 1);
        const _Float16* bufA = lds + (kt & 1) * 16384;
        const _Float16* bufB = bufA + 8192;
        #pragma unroll
        for (int ks = 0; ks < 2; ++ks) {
            const int sl = (ks << 2) | kc;
            half8 bf[4];
            #pragma unroll
            for (int n = 0; n < 4; ++n) {
                const int row = wc * 64 + n * 16 + fr;
                bf[n] = *(const half8*)(bufB + row * 64 + ((sl ^ (row & 7)) << 3));
            }
            #pragma unroll
            for (int m = 0; m < 4; ++m) {
                const int row = wr * 64 + m * 16 + fr;
                half8 af = *(const half8*)(bufA + row * 64 + ((sl ^ (row & 7)) << 3));
                #pragma unroll
                for (int n = 0; n < 4; ++n)
                    acc[m][n] = __builtin_amdgcn_mfma_f32_16x16x32_f16(af, bf[n], acc[m][n], 0, 0, 0);
            }
        }
        __syncthreads();   // drains prefetch (vmcnt 0) + releases buffers
    }

    float csum[4] = {0.f, 0.f, 0.f, 0.f};
    #pragma unroll
    for (int m = 0; m < 4; ++m) {
        const int gr0 = row0 + wr * 64 + m * 16 + kc * 4;
        #pragma unroll
        for (int n = 0; n < 4; ++n) {
            const int j = col0 + wc * 64 + n * 16 + fr;
            const float bj = bias[j];
            const int h = j >> 6, dd = j & 63;
            #pragma unroll
            for (int r2 = 0; r2 < 4; ++r2) {
                const int i = gr0 + r2;
                const int nn = i >> 11, l = i & (L_ - 1);
                float v = acc[m][n][r2] + bj;
                if (z < 2) { v = sigmoidf_(v); csum[n] += v; }
                outp[(((size_t)(nn * H_ + h)) * L_ + l) * HD_ + dd] = (_Float16)v;
            }
        }
    }

    if (z < 2) {
        float* scol = (float*)lds;             // LDS free after final barrier
        if (t < 128) scol[t] = 0.f;
        __syncthreads();
        #pragma unroll
        for (int n = 0; n < 4; ++n)
            atomicAdd(&scol[wc * 64 + n * 16 + fr], csum[n]);
        __syncthreads();
        if (t < 128) {
            const int j = col0 + t;
            const int nn = row0 >> 11;
            float* dst = (z == 0) ? qsum : ksum;
            atomicAdd(&dst[(nn * H_ + (j >> 6)) * 64 + (j & 63)], scol[t]);
        }
    }
}

// ===========================================================================
// Output GEMM: single-product f16, BK=64, 2-phase dbuf, XCD grid (512 = 8x64)
// (proven R13 — unchanged)
// ===========================================================================
__global__ __launch_bounds__(256) void gemm_out_kernel(
    const _Float16* __restrict__ af, const _Float16* __restrict__ wo,
    const float* __restrict__ bias, float* __restrict__ outp)
{
    const int bid = (int)blockIdx.x;
    const int wg = (bid & 7) * 64 + (bid >> 3);
    const int row0 = (wg >> 3) * 128;
    const int col0 = (wg & 7) * 128;

    __shared__ _Float16 lds[2 * 16384];
    const int t = threadIdx.x;
    const int lane = t & 63;
    const int w = t >> 6;
    const int wr = w >> 1, wc = w & 1;
    const int fr = lane & 15, kc = lane >> 4;

    auto STAGE = [&](int k0, int buf) {
        const _Float16* a_g = af + (size_t)row0 * DM + k0;
        const _Float16* b_g = wo + (size_t)col0 * DM + k0;
        _Float16* dst = lds + buf * 16384;
        #pragma unroll
        for (int p = 0; p < 4; ++p) {
            const int b = p * 4096 + t * 16;
            const int r = b >> 7;
            const int s = (b >> 4) & 7;
            const int c = ((s ^ (r & 7)) << 3);
            const size_t go = (size_t)r * DM + c;
            GLOAD16(a_g + go, dst + (b >> 1));
            GLOAD16(b_g + go, dst + 8192 + (b >> 1));
        }
    };

    f32x4 acc[4][4];
    #pragma unroll
    for (int m = 0; m < 4; ++m)
        #pragma unroll
        for (int n = 0; n < 4; ++n) acc[m][n] = f32x4{0.f, 0.f, 0.f, 0.f};

    STAGE(0, 0);
    __syncthreads();

    for (int kt = 0; kt < 16; ++kt) {
        if (kt + 1 < 16) STAGE((kt + 1) * 64, (kt + 1) & 1);
        const _Float16* bufA = lds + (kt & 1) * 16384;
        const _Float16* bufB = bufA + 8192;
        #pragma unroll
        for (int ks = 0; ks < 2; ++ks) {
            const int sl = (ks << 2) | kc;
            half8 bf[4];
            #pragma unroll
            for (int n = 0; n < 4; ++n) {
                const int row = wc * 64 + n * 16 + fr;
                bf[n] = *(const half8*)(bufB + row * 64 + ((sl ^ (row & 7)) << 3));
            }
            #pragma unroll
            for (int m = 0; m < 4; ++m) {
                const int row = wr * 64 + m * 16 + fr;
                half8 af8 = *(const half8*)(bufA + row * 64 + ((sl ^ (row & 7)) << 3));
                #pragma unroll
                for (int n = 0; n < 4; ++n)
                    acc[m][n] = __builtin_amdgcn_mfma_f32_16x16x32_f16(af8, bf[n], acc[m][n], 0, 0, 0);
            }
        }
        __syncthreads();
    }

    #pragma unroll
    for (int m = 0; m < 4; ++m) {
        const int gr0 = row0 + wr * 64 + m * 16 + kc * 4;
        #pragma unroll
        for (int n = 0; n < 4; ++n) {
            const int j = col0 + wc * 64 + n * 16 + fr;
            const float bj = bias[j];
            #pragma unroll
            for (int r2 = 0; r2 < 4; ++r2)
                outp[(size_t)(gr0 + r2) * DM + j] = acc[m][n][r2] + bj;
        }
    }
}

// ---------------------------------------------------------------------------
// stage1 — rowgroup-8 dots (proven R12)
// ---------------------------------------------------------------------------
__global__ __launch_bounds__(256) void stage1_kernel(
    const _Float16* __restrict__ q, const _Float16* __restrict__ k,
    const float* __restrict__ qsum, const float* __restrict__ ksum,
    float* __restrict__ si, float* __restrict__ qsi, float* __restrict__ kso)
{
    const int nh = blockIdx.x, ch = blockIdx.y;
    const _Float16* qp = q + (size_t)nh * L_ * HD_;
    const _Float16* kp = k + (size_t)nh * L_ * HD_;
    const int tid = threadIdx.x;
    const int lane = tid & 63;
    const int w = tid >> 6;
    const int r8 = lane >> 3;
    const int oct = lane & 7;

    __shared__ float ksum_s[64], qsum_s[64];
    __shared__ float s1[4][64], s2[4][64];
    if (tid < 64) {
        ksum_s[tid] = ksum[nh * 64 + tid] + EPS_;
        qsum_s[tid] = qsum[nh * 64 + tid] + EPS_;
    }
    __syncthreads();

    float qacc[8] = {0.f}, kacc[8] = {0.f};
    #pragma unroll
    for (int it = 0; it < 8; ++it) {
        const int l = ch * 256 + it * 32 + w * 8 + r8;
        half8 q8 = *(const half8*)(qp + (size_t)l * HD_ + oct * 8);
        half8 k8 = *(const half8*)(kp + (size_t)l * HD_ + oct * 8);
        float a = 0.f, b = 0.f;
        #pragma unroll
        for (int j = 0; j < 8; ++j) {
            a += ((float)q8[j] + EPS_) * ksum_s[oct * 8 + j];
            b += ((float)k8[j] + EPS_) * qsum_s[oct * 8 + j];
        }
        a += __shfl_xor(a, 1); a += __shfl_xor(a, 2); a += __shfl_xor(a, 4);
        b += __shfl_xor(b, 1); b += __shfl_xor(b, 2); b += __shfl_xor(b, 4);
        const float siv = 1.f / a;
        const float sov = 1.f / b;
        if (oct == 0) si[nh * L_ + l] = siv;
        #pragma unroll
        for (int j = 0; j < 8; ++j) {
            qacc[j] += (float)q8[j] * siv;
            kacc[j] += (float)k8[j] * sov;
        }
    }
    #pragma unroll
    for (int j = 0; j < 8; ++j) {
        qacc[j] += __shfl_xor(qacc[j], 8);  qacc[j] += __shfl_xor(qacc[j], 16); qacc[j] += __shfl_xor(qacc[j], 32);
        kacc[j] += __shfl_xor(kacc[j], 8);  kacc[j] += __shfl_xor(kacc[j], 16); kacc[j] += __shfl_xor(kacc[j], 32);
    }
    if (r8 == 0) {
        #pragma unroll
        for (int j = 0; j < 8; ++j) { s1[w][oct * 8 + j] = qacc[j]; s2[w][oct * 8 + j] = kacc[j]; }
    }
    __syncthreads();
    if (tid < 64) {
        atomicAdd(&qsi[nh * 64 + tid], s1[0][tid] + s1[1][tid] + s1[2][tid] + s1[3][tid]);
        atomicAdd(&kso[nh * 64 + tid], s2[0][tid] + s2[1][tid] + s2[2][tid] + s2[3][tid]);
    }
}

// ---------------------------------------------------------------------------
// kv partial with fused source-competition; atomicAdd into kvb (proven R13)
// ---------------------------------------------------------------------------
__global__ __launch_bounds__(256) void kv_part_kernel(
    const _Float16* __restrict__ k, const _Float16* __restrict__ v,
    const float* __restrict__ qsi, float* __restrict__ kvb, float* __restrict__ psum_p)
{
    const int nh = blockIdx.x, ch = blockIdx.y;
    const _Float16* kp = k + (size_t)nh * L_ * HD_;
    const _Float16* vp = v + (size_t)nh * L_ * HD_;
    const int tid = threadIdx.x;
    const int lane = tid & 63;
    const int w = tid >> 6;
    const int row8 = tid >> 3;
    const int oct = tid & 7;

    __shared__ float qsi_s[64];
    __shared__ float ks[32][65], vs[32][65];
    __shared__ float pl[32];
    if (tid < 64) qsi_s[tid] = qsi[nh * 64 + tid] + EPS_;
    __syncthreads();

    float acc[16] = {0.f};
    float psum_acc = 0.f;
    for (int l0 = ch * 256; l0 < (ch + 1) * 256; l0 += 32) {
        {
            const half8* kp8 = (const half8*)(kp + (size_t)l0 * HD_);
            const half8* vp8 = (const half8*)(vp + (size_t)l0 * HD_);
            half8 k8 = kp8[tid];
            half8 v8 = vp8[tid];
            const int r = tid >> 3, c = (tid & 7) * 8;
            #pragma unroll
            for (int j = 0; j < 8; ++j) {
                ks[r][c + j] = (float)k8[j];
                vs[r][c + j] = (float)v8[j];
            }
        }
        __syncthreads();
        {
            float b = 0.f;
            #pragma unroll
            for (int j = 0; j < 8; ++j)
                b += (ks[row8][oct * 8 + j] + EPS_) * qsi_s[oct * 8 + j];
            b += __shfl_xor(b, 1); b += __shfl_xor(b, 2); b += __shfl_xor(b, 4);
            b = fminf(1.f, fmaxf(-1.f, b));
            const float p = fexp_(b);
            if (oct == 0) { pl[row8] = p; psum_acc += p; }
        }
        __syncthreads();
        #pragma unroll 4
        for (int ll = 0; ll < 32; ++ll) {
            const float vv = vs[ll][lane] * pl[ll];
            #pragma unroll
            for (int dd = 0; dd < 16; ++dd) acc[dd] += ks[ll][w * 16 + dd] * vv;
        }
        __syncthreads();
    }
    #pragma unroll
    for (int dd = 0; dd < 16; ++dd)
        atomicAdd(&kvb[(size_t)nh * 4096 + (w * 16 + dd) * 64 + lane], acc[dd]);

    psum_acc += __shfl_xor(psum_acc, 8);
    psum_acc += __shfl_xor(psum_acc, 16);
    psum_acc += __shfl_xor(psum_acc, 32);
    psum_acc += __shfl_xor(psum_acc, 1);
    psum_acc += __shfl_xor(psum_acc, 2);
    psum_acc += __shfl_xor(psum_acc, 4);
    __shared__ float sp[4];
    if (lane == 0) sp[w] = psum_acc;
    __syncthreads();
    if (tid == 0) psum_p[nh * 8 + ch] = sp[0] + sp[1] + sp[2] + sp[3];
}

// ---------------------------------------------------------------------------
// out with fused sink_allocation + deferred softmax scale; f16 attn store
// ---------------------------------------------------------------------------
__global__ __launch_bounds__(256) void out_kernel(
    const _Float16* __restrict__ q, const float* __restrict__ kvb,
    const float* __restrict__ si, const float* __restrict__ kso,
    const float* __restrict__ psum_p,
    _Float16* __restrict__ attn_f)
{
    const int nh = blockIdx.x;
    const int n = nh >> 4;
    const int h = nh & 15;
    const int l0 = blockIdx.y * 64;
    __shared__ float kvs[64][64];
    __shared__ float qs[64][65];
    __shared__ float sal[64];
    __shared__ float kso_s[64];
    const int tid = threadIdx.x;
    float tot = 0.f;
    #pragma unroll
    for (int c = 0; c < 8; ++c) tot += psum_p[nh * 8 + c];
    const float scale = (float)L_ / tot;
    for (int i = tid; i < 4096; i += 256)
        kvs[i >> 6][i & 63] = kvb[(size_t)nh * 4096 + i];
    {
        const half8* src8 = (const half8*)(q + ((size_t)nh * L_ + l0) * HD_);
        for (int i = tid; i < 512; i += 256) {
            half8 v8 = src8[i];
            const int r = i >> 3, c = (i & 7) * 8;
            #pragma unroll
            for (int j = 0; j < 8; ++j) qs[r][c + j] = (float)v8[j];
        }
    }
    if (tid < 64) kso_s[tid] = kso[nh * 64 + tid] + EPS_;
    __syncthreads();
    {
        const int row = tid >> 3;           // 0..31
        const int oct = tid & 7;
        #pragma unroll
        for (int rr = 0; rr < 2; ++rr) {
            const int r = rr * 32 + row;
            float a = 0.f;
            #pragma unroll
            for (int j = 0; j < 8; ++j)
                a += (qs[r][oct * 8 + j] + EPS_) * kso_s[oct * 8 + j];
            a += __shfl_xor(a, 1); a += __shfl_xor(a, 2); a += __shfl_xor(a, 4);
            if (oct == 0) sal[r] = sigmoidf_(a);
        }
    }
    __syncthreads();
    const int lane = tid & 63;
    const int w = tid >> 6;
    for (int ll = w; ll < 64; ll += 4) {
        const int l = l0 + ll;
        float acc = 0.f;
        #pragma unroll
        for (int d = 0; d < 64; ++d) acc += qs[ll][d] * kvs[d][lane];
        const float val = acc * si[nh * L_ + l] * sal[ll] * scale;
        attn_f[((size_t)n * L_ + l) * DM + h * 64 + lane] = (_Float16)val;
    }
}

extern "C" void kernel_launch(void* const* d_in, const int* in_sizes, int n_in,
                              void* d_out, int out_size, void* d_ws, size_t ws_size,
                              hipStream_t stream)
{
    const float* x  = (const float*)d_in[0];
    const float* Wq = (const float*)d_in[1];
    const float* bq = (const float*)d_in[2];
    const float* Wk = (const float*)d_in[3];
    const float* bk = (const float*)d_in[4];
    const float* Wv = (const float*)d_in[5];
    const float* bv = (const float*)d_in[6];
    const float* Wo = (const float*)d_in[7];
    const float* bo = (const float*)d_in[8];
    float* out = (float*)d_out;

    float* ws = (float*)d_ws;
    size_t off = 0;
    const size_t big = (size_t)B_ * L_ * DM;   // 8,388,608 elems
    _Float16* qbuf = (_Float16*)(ws + off); off += big / 2;
    _Float16* kbuf = (_Float16*)(ws + off); off += big / 2;
    _Float16* vbuf = (_Float16*)(ws + off); off += big / 2;
    _Float16* xf = (_Float16*)(ws + off);
    _Float16* attn_f = xf;
    off += big / 2;
    _Float16* wh3 = (_Float16*)(ws + off); off += (size_t)3 * DM * DM / 2;
    _Float16* woh = (_Float16*)(ws + off); off += (size_t)DM * DM / 2;
    float* kvb    = ws + off; off += (size_t)NH_ * 64 * 64;
    float* sums = ws + off;
    float* qsum = sums;
    float* ksum = sums + 1 * NH_ * 64;
    float* qsi  = sums + 2 * NH_ * 64;
    float* kso  = sums + 3 * NH_ * 64;
    off += 4 * NH_ * 64;
    float* psum_p = ws + off; off += NH_ * 8;
    float* si     = ws + off; off += NH_ * L_;

    // 1. prep: x -> f16, weights -> f16, zero kvb + accumulators
    prep_kernel<<<12288, 256, 0, stream>>>(x, Wq, Wk, Wv, Wo, xf, wh3, woh, sums, kvb);

    // 2. QKV projection GEMM (R13 proven: 128x128, 2-phase dbuf, XCD swizzle)
    gemm_qkv_kernel<<<1536, 256, 0, stream>>>(xf, wh3, bq, bk, bv,
                                              qbuf, kbuf, vbuf, qsum, ksum);

    // 3. stage1 (rowgroup dots; si + qsi/kso atomics)
    stage1_kernel<<<dim3(NH_, 8), 256, 0, stream>>>(qbuf, kbuf, qsum, ksum, si, qsi, kso);

    // 4. kv with fused source-competition -> atomicAdd into kvb
    kv_part_kernel<<<dim3(NH_, 8), 256, 0, stream>>>(kbuf, vbuf, qsi, kvb, psum_p);

    // 5. out with fused sink_allocation + softmax scale -> f16 attn
    out_kernel<<<dim3(NH_, L_ / 64), 256, 0, stream>>>(qbuf, kvb, si, kso, psum_p, attn_f);

    // 6. output projection GEMM (2-phase dbuf, single-product f16)
    gemm_out_kernel<<<512, 256, 0, stream>>>(attn_f, woh, bo, out);
}